// Round 1
// baseline (1139.082 us; speedup 1.0000x reference)
//
#include <hip/hip_runtime.h>
#include <math.h>

// Problem: N=2048, DH=256, DK=64, FF=32, all fp32.
// ws layout (floats):
//   q  : [0,        131072)   2048 x 64
//   k  : [131072,   262144)   2048 x 64
//   v  : [262144,   786432)   2048 x 256
//   sc : [786432,  4980736)   2048 x 2048 (scores, overwritten in-place with focus)
// total ~19.9 MB of ws.

#define NN  2048
#define DHH 256
#define DKK 64

// ---------------------------------------------------------------------------
// K1: qkv = x @ [Wq | Wk | Wv] + bias.  Tiled 64x64, TK=32.
// grid (32, 6): y=0 -> q cols, y=1 -> k cols, y=2..5 -> v cols.
// ---------------------------------------------------------------------------
__global__ __launch_bounds__(256) void k_qkv(
    const float* __restrict__ x,
    const float* __restrict__ Wq, const float* __restrict__ bq,
    const float* __restrict__ Wk, const float* __restrict__ bk,
    const float* __restrict__ Wv, const float* __restrict__ bv,
    float* __restrict__ qm, float* __restrict__ km, float* __restrict__ vm)
{
    __shared__ float As[32][64];   // [kk][row]  (x tile, transposed)
    __shared__ float Bs[32][64];   // [kk][col]  (W tile)

    const int t  = threadIdx.x;
    const int m0 = blockIdx.x * 64;
    const int yb = blockIdx.y;

    const float* W; const float* bias; int wld; int cw0; float* outp; int old;
    if (yb == 0)      { W = Wq; bias = bq; wld = 64;  cw0 = 0;            outp = qm; old = 64;  }
    else if (yb == 1) { W = Wk; bias = bk; wld = 64;  cw0 = 0;            outp = km; old = 64;  }
    else              { W = Wv; bias = bv; wld = 256; cw0 = (yb - 2)*64;  outp = vm; old = 256; }

    const int tx = t & 15, ty = t >> 4;
    float acc[4][4] = {};

    for (int k0 = 0; k0 < DHH; k0 += 32) {
        // stage x tile: rows m0..m0+63, k cols k0..k0+31  -> As[kk][row]
        {
            const int rr = t >> 3;          // 0..31
            const int cc = (t & 7) * 4;     // 0..28
            float4 a0 = *(const float4*)(x + (size_t)(m0 + rr)      * DHH + k0 + cc);
            float4 a1 = *(const float4*)(x + (size_t)(m0 + rr + 32) * DHH + k0 + cc);
            As[cc+0][rr]    = a0.x; As[cc+1][rr]    = a0.y; As[cc+2][rr]    = a0.z; As[cc+3][rr]    = a0.w;
            As[cc+0][rr+32] = a1.x; As[cc+1][rr+32] = a1.y; As[cc+2][rr+32] = a1.z; As[cc+3][rr+32] = a1.w;
        }
        // stage W tile: k rows k0..k0+31, cols cw0..cw0+63 -> Bs[kk][col]
        {
            const int bk_ = t >> 4;         // 0..15
            const int bc  = (t & 15) * 4;   // 0..60
            *(float4*)&Bs[bk_][bc]      = *(const float4*)(W + (size_t)(k0 + bk_)      * wld + cw0 + bc);
            *(float4*)&Bs[bk_ + 16][bc] = *(const float4*)(W + (size_t)(k0 + bk_ + 16) * wld + cw0 + bc);
        }
        __syncthreads();
        #pragma unroll
        for (int kk = 0; kk < 32; ++kk) {
            float4 a = *(const float4*)&As[kk][ty * 4];
            float4 b = *(const float4*)&Bs[kk][tx * 4];
            float av[4] = {a.x, a.y, a.z, a.w};
            float bw[4] = {b.x, b.y, b.z, b.w};
            #pragma unroll
            for (int ii = 0; ii < 4; ++ii)
                #pragma unroll
                for (int jj = 0; jj < 4; ++jj)
                    acc[ii][jj] = fmaf(av[ii], bw[jj], acc[ii][jj]);
        }
        __syncthreads();
    }

    float4 b4 = *(const float4*)&bias[cw0 + tx * 4];
    #pragma unroll
    for (int ii = 0; ii < 4; ++ii) {
        const int gr = m0 + ty * 4 + ii;
        float4 r;
        r.x = acc[ii][0] + b4.x; r.y = acc[ii][1] + b4.y;
        r.z = acc[ii][2] + b4.z; r.w = acc[ii][3] + b4.w;
        *(float4*)(outp + (size_t)gr * old + cw0 + tx * 4) = r;
    }
}

// ---------------------------------------------------------------------------
// K2: scores[i][j] = dot(k_i, q_j)  (NT GEMM, K=64 single-stage, 64x64 tiles)
// grid (32, 32): x = j tile, y = i tile.
// ---------------------------------------------------------------------------
__global__ __launch_bounds__(256) void k_scores(
    const float* __restrict__ qm, const float* __restrict__ km, float* __restrict__ sc)
{
    __shared__ float Ks[64][64];   // [kk][i]
    __shared__ float Qs[64][64];   // [kk][j]

    const int t  = threadIdx.x;
    const int j0 = blockIdx.x * 64;
    const int i0 = blockIdx.y * 64;
    const int lane = t & 63, wv = t >> 6;

    // lane-based transposing load: conflict-free LDS stores (2-way, free)
    #pragma unroll
    for (int p = 0; p < 4; ++p) {
        const int cc = (wv + 4 * p) * 4;   // 16 col-groups of 4
        float4 gk = *(const float4*)(km + (size_t)(i0 + lane) * DKK + cc);
        Ks[cc+0][lane] = gk.x; Ks[cc+1][lane] = gk.y; Ks[cc+2][lane] = gk.z; Ks[cc+3][lane] = gk.w;
        float4 gq = *(const float4*)(qm + (size_t)(j0 + lane) * DKK + cc);
        Qs[cc+0][lane] = gq.x; Qs[cc+1][lane] = gq.y; Qs[cc+2][lane] = gq.z; Qs[cc+3][lane] = gq.w;
    }
    __syncthreads();

    const int tx = t & 15, ty = t >> 4;
    float acc[4][4] = {};
    #pragma unroll
    for (int kk = 0; kk < 64; ++kk) {
        float4 a = *(const float4*)&Ks[kk][ty * 4];
        float4 b = *(const float4*)&Qs[kk][tx * 4];
        float av[4] = {a.x, a.y, a.z, a.w};
        float bw[4] = {b.x, b.y, b.z, b.w};
        #pragma unroll
        for (int ii = 0; ii < 4; ++ii)
            #pragma unroll
            for (int jj = 0; jj < 4; ++jj)
                acc[ii][jj] = fmaf(av[ii], bw[jj], acc[ii][jj]);
    }

    #pragma unroll
    for (int ii = 0; ii < 4; ++ii) {
        float4 r = {acc[ii][0], acc[ii][1], acc[ii][2], acc[ii][3]};
        *(float4*)(sc + (size_t)(i0 + ty * 4 + ii) * NN + j0 + tx * 4) = r;
    }
}

// ---------------------------------------------------------------------------
// K3: per-edge MLP + row softmax. One block per row i; 256 threads; each
// thread handles 8 j's, processed in pairs to amortize W2 LDS reads.
// Writes focus (normalized) in-place over sc.
// ---------------------------------------------------------------------------
__global__ __launch_bounds__(256) void k_mlp(
    float* __restrict__ sc, const float* __restrict__ adj, const float* __restrict__ dense,
    const float* __restrict__ W1, const float* __restrict__ b1,
    const float* __restrict__ W2, const float* __restrict__ b2,
    const float* __restrict__ W3, const float* __restrict__ b3)
{
    __shared__ float W1s[96];
    __shared__ float b1s[32];
    __shared__ float W2s[1024];
    __shared__ float b2s[32];
    __shared__ float W3s[32];
    __shared__ float redmax[4];
    __shared__ float redsum[4];

    const int t = threadIdx.x;
    const int i = blockIdx.x;

    if (t < 96) W1s[t] = W1[t];
    if (t < 32) { b1s[t] = b1[t]; b2s[t] = b2[t]; W3s[t] = W3[t]; }
    *(float4*)&W2s[t * 4] = *(const float4*)&W2[t * 4];
    __syncthreads();

    const float b3v = b3[0];
    float*       srow = sc    + (size_t)i * NN;
    const float* arow = adj   + (size_t)i * NN;
    const float* drow = dense + (size_t)i * NN;

    float lg[8];
    float lmax = -1e30f;

    #pragma unroll
    for (int u = 0; u < 4; ++u) {
        const int j0 = t + u * 512;
        const float s0 = srow[j0],       a0 = arow[j0],       d0 = drow[j0];
        const float s1 = srow[j0 + 256], a1 = arow[j0 + 256], d1 = drow[j0 + 256];

        // layer 1: feats(3) -> 32, relu
        float h0[32], h1[32];
        #pragma unroll
        for (int o = 0; o < 32; o += 4) {
            float4 wa = *(const float4*)&W1s[o];
            float4 wb = *(const float4*)&W1s[32 + o];
            float4 wc = *(const float4*)&W1s[64 + o];
            float4 bb = *(const float4*)&b1s[o];
            h0[o+0] = fmaxf(0.f, fmaf(s0, wa.x, fmaf(a0, wb.x, fmaf(d0, wc.x, bb.x))));
            h0[o+1] = fmaxf(0.f, fmaf(s0, wa.y, fmaf(a0, wb.y, fmaf(d0, wc.y, bb.y))));
            h0[o+2] = fmaxf(0.f, fmaf(s0, wa.z, fmaf(a0, wb.z, fmaf(d0, wc.z, bb.z))));
            h0[o+3] = fmaxf(0.f, fmaf(s0, wa.w, fmaf(a0, wb.w, fmaf(d0, wc.w, bb.w))));
            h1[o+0] = fmaxf(0.f, fmaf(s1, wa.x, fmaf(a1, wb.x, fmaf(d1, wc.x, bb.x))));
            h1[o+1] = fmaxf(0.f, fmaf(s1, wa.y, fmaf(a1, wb.y, fmaf(d1, wc.y, bb.y))));
            h1[o+2] = fmaxf(0.f, fmaf(s1, wa.z, fmaf(a1, wb.z, fmaf(d1, wc.z, bb.z))));
            h1[o+3] = fmaxf(0.f, fmaf(s1, wa.w, fmaf(a1, wb.w, fmaf(d1, wc.w, bb.w))));
        }

        // layer 2: 32 -> 32 (1024 MACs/edge; W2 float4 LDS broadcasts shared by 2 edges)
        float acc0[32], acc1[32];
        #pragma unroll
        for (int o = 0; o < 32; o += 4) {
            float4 bb = *(const float4*)&b2s[o];
            acc0[o] = bb.x; acc0[o+1] = bb.y; acc0[o+2] = bb.z; acc0[o+3] = bb.w;
            acc1[o] = bb.x; acc1[o+1] = bb.y; acc1[o+2] = bb.z; acc1[o+3] = bb.w;
        }
        #pragma unroll
        for (int kk = 0; kk < 32; ++kk) {
            const float ha = h0[kk], hb = h1[kk];
            #pragma unroll
            for (int o = 0; o < 32; o += 4) {
                float4 w = *(const float4*)&W2s[kk * 32 + o];
                acc0[o]   = fmaf(ha, w.x, acc0[o]);
                acc0[o+1] = fmaf(ha, w.y, acc0[o+1]);
                acc0[o+2] = fmaf(ha, w.z, acc0[o+2]);
                acc0[o+3] = fmaf(ha, w.w, acc0[o+3]);
                acc1[o]   = fmaf(hb, w.x, acc1[o]);
                acc1[o+1] = fmaf(hb, w.y, acc1[o+1]);
                acc1[o+2] = fmaf(hb, w.z, acc1[o+2]);
                acc1[o+3] = fmaf(hb, w.w, acc1[o+3]);
            }
        }

        // layer 3: relu then 32 -> 1
        float l0 = b3v, l1 = b3v;
        #pragma unroll
        for (int o = 0; o < 32; ++o) {
            l0 = fmaf(fmaxf(acc0[o], 0.f), W3s[o], l0);
            l1 = fmaf(fmaxf(acc1[o], 0.f), W3s[o], l1);
        }
        lg[2*u]   = l0;
        lg[2*u+1] = l1;
        lmax = fmaxf(lmax, fmaxf(l0, l1));
    }

    // block-wide max (wave64 shuffle + 4-wave LDS)
    #pragma unroll
    for (int off = 32; off > 0; off >>= 1)
        lmax = fmaxf(lmax, __shfl_xor(lmax, off, 64));
    const int lane = t & 63, wid = t >> 6;
    if (lane == 0) redmax[wid] = lmax;
    __syncthreads();
    const float rmax = fmaxf(fmaxf(redmax[0], redmax[1]), fmaxf(redmax[2], redmax[3]));

    float wgt[8];
    float lsum = 0.f;
    #pragma unroll
    for (int u = 0; u < 8; ++u) { wgt[u] = __expf(lg[u] - rmax); lsum += wgt[u]; }
    #pragma unroll
    for (int off = 32; off > 0; off >>= 1)
        lsum += __shfl_xor(lsum, off, 64);
    if (lane == 0) redsum[wid] = lsum;
    __syncthreads();
    const float inv = 1.f / (redsum[0] + redsum[1] + redsum[2] + redsum[3]);

    #pragma unroll
    for (int u = 0; u < 4; ++u) {
        const int j0 = t + u * 512;
        srow[j0]       = wgt[2*u]   * inv;
        srow[j0 + 256] = wgt[2*u+1] * inv;
    }
}

// ---------------------------------------------------------------------------
// K4: feature = focus @ v   (M=2048, N=256, K=2048). Tile 32x64, TK=32.
// grid (4, 64).
// ---------------------------------------------------------------------------
__global__ __launch_bounds__(256) void k_feat(
    const float* __restrict__ focus, const float* __restrict__ vm, float* __restrict__ out)
{
    __shared__ float Fs[32][32];   // [kk][m]
    __shared__ float Vs[32][64];   // [kk][n]

    const int t  = threadIdx.x;
    const int n0 = blockIdx.x * 64;
    const int m0 = blockIdx.y * 32;
    const int tx = t & 15, ty = t >> 4;

    float acc[2][4] = {};

    for (int k0 = 0; k0 < NN; k0 += 32) {
        {
            const int rr = t >> 3;        // 0..31 (m)
            const int cc = (t & 7) * 4;   // 0..28 (kk)
            float4 f = *(const float4*)(focus + (size_t)(m0 + rr) * NN + k0 + cc);
            Fs[cc+0][rr] = f.x; Fs[cc+1][rr] = f.y; Fs[cc+2][rr] = f.z; Fs[cc+3][rr] = f.w;

            const int vk = t >> 4;        // 0..15
            const int vc = (t & 15) * 4;  // 0..60
            *(float4*)&Vs[vk][vc]      = *(const float4*)(vm + (size_t)(k0 + vk)      * DHH + n0 + vc);
            *(float4*)&Vs[vk + 16][vc] = *(const float4*)(vm + (size_t)(k0 + vk + 16) * DHH + n0 + vc);
        }
        __syncthreads();
        #pragma unroll
        for (int kk = 0; kk < 32; ++kk) {
            float2 a = *(const float2*)&Fs[kk][ty * 2];
            float4 b = *(const float4*)&Vs[kk][tx * 4];
            acc[0][0] = fmaf(a.x, b.x, acc[0][0]);
            acc[0][1] = fmaf(a.x, b.y, acc[0][1]);
            acc[0][2] = fmaf(a.x, b.z, acc[0][2]);
            acc[0][3] = fmaf(a.x, b.w, acc[0][3]);
            acc[1][0] = fmaf(a.y, b.x, acc[1][0]);
            acc[1][1] = fmaf(a.y, b.y, acc[1][1]);
            acc[1][2] = fmaf(a.y, b.z, acc[1][2]);
            acc[1][3] = fmaf(a.y, b.w, acc[1][3]);
        }
        __syncthreads();
    }

    #pragma unroll
    for (int ii = 0; ii < 2; ++ii) {
        float4 r = {acc[ii][0], acc[ii][1], acc[ii][2], acc[ii][3]};
        *(float4*)(out + (size_t)(m0 + ty * 2 + ii) * DHH + n0 + tx * 4) = r;
    }
}

// ---------------------------------------------------------------------------
extern "C" void kernel_launch(void* const* d_in, const int* in_sizes, int n_in,
                              void* d_out, int out_size, void* d_ws, size_t ws_size,
                              hipStream_t stream) {
    const float* x     = (const float*)d_in[0];
    const float* adj   = (const float*)d_in[1];
    const float* dense = (const float*)d_in[2];
    const float* Wq    = (const float*)d_in[3];
    const float* bq    = (const float*)d_in[4];
    const float* Wk    = (const float*)d_in[5];
    const float* bk    = (const float*)d_in[6];
    const float* Wv    = (const float*)d_in[7];
    const float* bv    = (const float*)d_in[8];
    const float* W1    = (const float*)d_in[9];
    const float* b1    = (const float*)d_in[10];
    const float* W2    = (const float*)d_in[11];
    const float* b2    = (const float*)d_in[12];
    const float* W3    = (const float*)d_in[13];
    const float* b3    = (const float*)d_in[14];
    float* out = (float*)d_out;
    float* ws  = (float*)d_ws;

    float* qm = ws;
    float* km = ws + 131072;
    float* vm = ws + 262144;
    float* sc = ws + 786432;   // 2048*2048, ~16.8 MB; ws total use ~19.9 MB

    hipLaunchKernelGGL(k_qkv,    dim3(32, 6),  dim3(256), 0, stream,
                       x, Wq, bq, Wk, bk, Wv, bv, qm, km, vm);
    hipLaunchKernelGGL(k_scores, dim3(32, 32), dim3(256), 0, stream, qm, km, sc);
    hipLaunchKernelGGL(k_mlp,    dim3(2048),   dim3(256), 0, stream,
                       sc, adj, dense, W1, b1, W2, b2, W3, b3);
    hipLaunchKernelGGL(k_feat,   dim3(4, 64),  dim3(256), 0, stream, sc, vm, out);
}

// Round 2
// 270.352 us; speedup vs baseline: 4.2133x; 4.2133x over previous
//
#include <hip/hip_runtime.h>
#include <math.h>

// Problem: N=2048, DH=256, DK=64, FF=32, fp32 in/out.
// ws layout (floats):
//   q  : [0,        131072)   2048 x 64
//   k  : [131072,   262144)   2048 x 64
//   v  : [262144,   786432)   2048 x 256
//   sc : [786432,  4980736)   2048 x 2048 (scores, overwritten in-place with focus)

#define NN  2048
#define DHH 256
#define DKK 64

typedef float  f32x4  __attribute__((ext_vector_type(4)));
typedef _Float16 f16x8 __attribute__((ext_vector_type(8)));
typedef _Float16 f16x2 __attribute__((ext_vector_type(2)));

// ---------------------------------------------------------------------------
// K1: qkv = x @ [Wq | Wk | Wv] + bias.  Tiled 64x64, TK=32. (unchanged)
// ---------------------------------------------------------------------------
__global__ __launch_bounds__(256) void k_qkv(
    const float* __restrict__ x,
    const float* __restrict__ Wq, const float* __restrict__ bq,
    const float* __restrict__ Wk, const float* __restrict__ bk,
    const float* __restrict__ Wv, const float* __restrict__ bv,
    float* __restrict__ qm, float* __restrict__ km, float* __restrict__ vm)
{
    __shared__ float As[32][64];
    __shared__ float Bs[32][64];

    const int t  = threadIdx.x;
    const int m0 = blockIdx.x * 64;
    const int yb = blockIdx.y;

    const float* W; const float* bias; int wld; int cw0; float* outp; int old;
    if (yb == 0)      { W = Wq; bias = bq; wld = 64;  cw0 = 0;            outp = qm; old = 64;  }
    else if (yb == 1) { W = Wk; bias = bk; wld = 64;  cw0 = 0;            outp = km; old = 64;  }
    else              { W = Wv; bias = bv; wld = 256; cw0 = (yb - 2)*64;  outp = vm; old = 256; }

    const int tx = t & 15, ty = t >> 4;
    float acc[4][4] = {};

    for (int k0 = 0; k0 < DHH; k0 += 32) {
        {
            const int rr = t >> 3;
            const int cc = (t & 7) * 4;
            float4 a0 = *(const float4*)(x + (size_t)(m0 + rr)      * DHH + k0 + cc);
            float4 a1 = *(const float4*)(x + (size_t)(m0 + rr + 32) * DHH + k0 + cc);
            As[cc+0][rr]    = a0.x; As[cc+1][rr]    = a0.y; As[cc+2][rr]    = a0.z; As[cc+3][rr]    = a0.w;
            As[cc+0][rr+32] = a1.x; As[cc+1][rr+32] = a1.y; As[cc+2][rr+32] = a1.z; As[cc+3][rr+32] = a1.w;
        }
        {
            const int bk_ = t >> 4;
            const int bc  = (t & 15) * 4;
            *(float4*)&Bs[bk_][bc]      = *(const float4*)(W + (size_t)(k0 + bk_)      * wld + cw0 + bc);
            *(float4*)&Bs[bk_ + 16][bc] = *(const float4*)(W + (size_t)(k0 + bk_ + 16) * wld + cw0 + bc);
        }
        __syncthreads();
        #pragma unroll
        for (int kk = 0; kk < 32; ++kk) {
            float4 a = *(const float4*)&As[kk][ty * 4];
            float4 b = *(const float4*)&Bs[kk][tx * 4];
            float av[4] = {a.x, a.y, a.z, a.w};
            float bw[4] = {b.x, b.y, b.z, b.w};
            #pragma unroll
            for (int ii = 0; ii < 4; ++ii)
                #pragma unroll
                for (int jj = 0; jj < 4; ++jj)
                    acc[ii][jj] = fmaf(av[ii], bw[jj], acc[ii][jj]);
        }
        __syncthreads();
    }

    float4 b4 = *(const float4*)&bias[cw0 + tx * 4];
    #pragma unroll
    for (int ii = 0; ii < 4; ++ii) {
        const int gr = m0 + ty * 4 + ii;
        float4 r;
        r.x = acc[ii][0] + b4.x; r.y = acc[ii][1] + b4.y;
        r.z = acc[ii][2] + b4.z; r.w = acc[ii][3] + b4.w;
        *(float4*)(outp + (size_t)gr * old + cw0 + tx * 4) = r;
    }
}

// ---------------------------------------------------------------------------
// K2: scores[i][j] = dot(k_i, q_j). (unchanged)
// ---------------------------------------------------------------------------
__global__ __launch_bounds__(256) void k_scores(
    const float* __restrict__ qm, const float* __restrict__ km, float* __restrict__ sc)
{
    __shared__ float Ks[64][64];
    __shared__ float Qs[64][64];

    const int t  = threadIdx.x;
    const int j0 = blockIdx.x * 64;
    const int i0 = blockIdx.y * 64;
    const int lane = t & 63, wv = t >> 6;

    #pragma unroll
    for (int p = 0; p < 4; ++p) {
        const int cc = (wv + 4 * p) * 4;
        float4 gk = *(const float4*)(km + (size_t)(i0 + lane) * DKK + cc);
        Ks[cc+0][lane] = gk.x; Ks[cc+1][lane] = gk.y; Ks[cc+2][lane] = gk.z; Ks[cc+3][lane] = gk.w;
        float4 gq = *(const float4*)(qm + (size_t)(j0 + lane) * DKK + cc);
        Qs[cc+0][lane] = gq.x; Qs[cc+1][lane] = gq.y; Qs[cc+2][lane] = gq.z; Qs[cc+3][lane] = gq.w;
    }
    __syncthreads();

    const int tx = t & 15, ty = t >> 4;
    float acc[4][4] = {};
    #pragma unroll
    for (int kk = 0; kk < 64; ++kk) {
        float4 a = *(const float4*)&Ks[kk][ty * 4];
        float4 b = *(const float4*)&Qs[kk][tx * 4];
        float av[4] = {a.x, a.y, a.z, a.w};
        float bw[4] = {b.x, b.y, b.z, b.w};
        #pragma unroll
        for (int ii = 0; ii < 4; ++ii)
            #pragma unroll
            for (int jj = 0; jj < 4; ++jj)
                acc[ii][jj] = fmaf(av[ii], bw[jj], acc[ii][jj]);
    }

    #pragma unroll
    for (int ii = 0; ii < 4; ++ii) {
        float4 r = {acc[ii][0], acc[ii][1], acc[ii][2], acc[ii][3]};
        *(float4*)(sc + (size_t)(i0 + ty * 4 + ii) * NN + j0 + tx * 4) = r;
    }
}

// ---------------------------------------------------------------------------
// K3 (REWRITTEN): per-edge MLP via fp16 MFMA + fused row softmax.
// One block per row i, 256 threads = 4 waves; wave w owns j in [w*512,(w+1)*512).
// Layer 1 (3->32): MFMA 16x16x32 with K-padded A = {s,a,d,0...}, B = W1 rows 0..2.
//   Two MFMAs produce even / odd output columns so each lane packs an adjacent
//   (2n, 2n+1) fp16 pair -> single ds_write_b32 into the h staging buffer.
// Layer 2 (32->32): MFMA with A = h from LDS (stride 40 halves = 80 B, 2-way
//   bank aliasing = free), B = W2 halves; epilogue relu+b2, dot W3 via
//   16-lane shuffle reduction -> logits in LDS; then block softmax.
// ---------------------------------------------------------------------------
__global__ __launch_bounds__(256) void k_mlp(
    float* __restrict__ sc, const float* __restrict__ adj, const float* __restrict__ dense,
    const float* __restrict__ W1, const float* __restrict__ b1,
    const float* __restrict__ W2, const float* __restrict__ b2,
    const float* __restrict__ W3, const float* __restrict__ b3)
{
    __shared__ _Float16 hsh[4 * 64 * 40];   // per-wave 64 rows x 40 halves (32 used)
    __shared__ float    lsg[NN];            // logits for the whole row
    __shared__ float    red[8];             // [0..3] max, [4..7] sum

    const int t    = threadIdx.x;
    const int lane = t & 63;
    const int w    = t >> 6;          // wave id 0..3
    const int col  = lane & 15;       // MFMA col / A-row lane
    const int q    = lane >> 4;       // quad 0..3
    const int i    = blockIdx.x;
    const int wbase = w * 64 * 40;    // halves

    // ---- loop-invariant fragments & per-lane constants ----
    // Layer-1 B frags: B[k][n], k=q*8+j, nonzero only k<3. half0 -> col 2n, half1 -> col 2n+1.
    f16x8 w1f0 = {0,0,0,0,0,0,0,0}, w1f1 = {0,0,0,0,0,0,0,0};
    if (q == 0) {
        const int ne = 2 * col, no = 2 * col + 1;
        w1f0[0] = (_Float16)W1[0*32 + ne]; w1f0[1] = (_Float16)W1[1*32 + ne]; w1f0[2] = (_Float16)W1[2*32 + ne];
        w1f1[0] = (_Float16)W1[0*32 + no]; w1f1[1] = (_Float16)W1[1*32 + no]; w1f1[2] = (_Float16)W1[2*32 + no];
    }
    // Layer-2 B frags: w2f0 -> cols 0..15, w2f1 -> cols 16..31.
    f16x8 w2f0, w2f1;
    #pragma unroll
    for (int j = 0; j < 8; ++j) {
        w2f0[j] = (_Float16)W2[(q * 8 + j) * 32 + col];
        w2f1[j] = (_Float16)W2[(q * 8 + j) * 32 + col + 16];
    }
    const float b1e = b1[2 * col], b1o = b1[2 * col + 1];
    const float b2a = b2[col],     b2b = b2[col + 16];
    const float w3a = W3[col],     w3b = W3[col + 16];
    const float b3v = b3[0];

    float*       srow = sc    + (size_t)i * NN;
    const float* arow = adj   + (size_t)i * NN;
    const float* drow = dense + (size_t)i * NN;

    const f32x4 zero4 = {0.f, 0.f, 0.f, 0.f};

    for (int c = 0; c < 8; ++c) {
        const int jj = w * 512 + c * 64 + lane;
        const float sval = srow[jj];
        const float aval = arow[jj];
        const float dval = drow[jj];

        // ---- layer 1: 4 MFMA steps of 16 edges each ----
        #pragma unroll
        for (int st = 0; st < 4; ++st) {
            const int srcl = st * 16 + col;
            const _Float16 sh = (_Float16)__shfl(sval, srcl, 64);
            const _Float16 ah = (_Float16)__shfl(aval, srcl, 64);
            const _Float16 dh = (_Float16)__shfl(dval, srcl, 64);
            f16x8 af = {sh, ah, dh, (_Float16)0, (_Float16)0, (_Float16)0, (_Float16)0, (_Float16)0};
            f32x4 hp0 = __builtin_amdgcn_mfma_f32_16x16x32_f16(af, w1f0, zero4, 0, 0, 0);
            f32x4 hp1 = __builtin_amdgcn_mfma_f32_16x16x32_f16(af, w1f1, zero4, 0, 0, 0);
            #pragma unroll
            for (int r = 0; r < 4; ++r) {
                const int e = st * 16 + q * 4 + r;      // edge row in this chunk
                f16x2 pk;
                pk[0] = (_Float16)fmaxf(hp0[r] + b1e, 0.f);
                pk[1] = (_Float16)fmaxf(hp1[r] + b1o, 0.f);
                *(f16x2*)&hsh[wbase + e * 40 + col * 2] = pk;
            }
        }
        __syncthreads();

        // ---- layer 2 + layer 3 ----
        #pragma unroll
        for (int st = 0; st < 4; ++st) {
            const int row = st * 16 + col;
            f16x8 a2 = *(const f16x8*)&hsh[wbase + row * 40 + q * 8];
            f32x4 acc0 = __builtin_amdgcn_mfma_f32_16x16x32_f16(a2, w2f0, zero4, 0, 0, 0);
            f32x4 acc1 = __builtin_amdgcn_mfma_f32_16x16x32_f16(a2, w2f1, zero4, 0, 0, 0);
            float p[4];
            #pragma unroll
            for (int r = 0; r < 4; ++r)
                p[r] = fmaxf(acc0[r] + b2a, 0.f) * w3a + fmaxf(acc1[r] + b2b, 0.f) * w3b;
            #pragma unroll
            for (int m = 1; m < 16; m <<= 1) {
                #pragma unroll
                for (int r = 0; r < 4; ++r)
                    p[r] += __shfl_xor(p[r], m, 64);
            }
            if (col == 0) {
                float4 lg = {p[0] + b3v, p[1] + b3v, p[2] + b3v, p[3] + b3v};
                *(float4*)&lsg[w * 512 + c * 64 + st * 16 + q * 4] = lg;
            }
        }
        __syncthreads();   // protects h staging WAR + logits visibility
    }

    // ---- row softmax over 2048 logits ----
    float lv[8], lmax = -1e30f;
    #pragma unroll
    for (int u = 0; u < 8; ++u) { lv[u] = lsg[t + u * 256]; lmax = fmaxf(lmax, lv[u]); }
    #pragma unroll
    for (int off = 32; off > 0; off >>= 1)
        lmax = fmaxf(lmax, __shfl_xor(lmax, off, 64));
    if (lane == 0) red[w] = lmax;
    __syncthreads();
    const float rmax = fmaxf(fmaxf(red[0], red[1]), fmaxf(red[2], red[3]));

    float wgt[8], lsum = 0.f;
    #pragma unroll
    for (int u = 0; u < 8; ++u) { wgt[u] = __expf(lv[u] - rmax); lsum += wgt[u]; }
    #pragma unroll
    for (int off = 32; off > 0; off >>= 1)
        lsum += __shfl_xor(lsum, off, 64);
    if (lane == 0) red[4 + w] = lsum;
    __syncthreads();
    const float inv = 1.f / (red[4] + red[5] + red[6] + red[7]);

    #pragma unroll
    for (int u = 0; u < 8; ++u)
        srow[t + u * 256] = wgt[u] * inv;
}

// ---------------------------------------------------------------------------
// K4: feature = focus @ v. (unchanged)
// ---------------------------------------------------------------------------
__global__ __launch_bounds__(256) void k_feat(
    const float* __restrict__ focus, const float* __restrict__ vm, float* __restrict__ out)
{
    __shared__ float Fs[32][32];
    __shared__ float Vs[32][64];

    const int t  = threadIdx.x;
    const int n0 = blockIdx.x * 64;
    const int m0 = blockIdx.y * 32;
    const int tx = t & 15, ty = t >> 4;

    float acc[2][4] = {};

    for (int k0 = 0; k0 < NN; k0 += 32) {
        {
            const int rr = t >> 3;
            const int cc = (t & 7) * 4;
            float4 f = *(const float4*)(focus + (size_t)(m0 + rr) * NN + k0 + cc);
            Fs[cc+0][rr] = f.x; Fs[cc+1][rr] = f.y; Fs[cc+2][rr] = f.z; Fs[cc+3][rr] = f.w;

            const int vk = t >> 4;
            const int vc = (t & 15) * 4;
            *(float4*)&Vs[vk][vc]      = *(const float4*)(vm + (size_t)(k0 + vk)      * DHH + n0 + vc);
            *(float4*)&Vs[vk + 16][vc] = *(const float4*)(vm + (size_t)(k0 + vk + 16) * DHH + n0 + vc);
        }
        __syncthreads();
        #pragma unroll
        for (int kk = 0; kk < 32; ++kk) {
            float2 a = *(const float2*)&Fs[kk][ty * 2];
            float4 b = *(const float4*)&Vs[kk][tx * 4];
            acc[0][0] = fmaf(a.x, b.x, acc[0][0]);
            acc[0][1] = fmaf(a.x, b.y, acc[0][1]);
            acc[0][2] = fmaf(a.x, b.z, acc[0][2]);
            acc[0][3] = fmaf(a.x, b.w, acc[0][3]);
            acc[1][0] = fmaf(a.y, b.x, acc[1][0]);
            acc[1][1] = fmaf(a.y, b.y, acc[1][1]);
            acc[1][2] = fmaf(a.y, b.z, acc[1][2]);
            acc[1][3] = fmaf(a.y, b.w, acc[1][3]);
        }
        __syncthreads();
    }

    #pragma unroll
    for (int ii = 0; ii < 2; ++ii) {
        float4 r = {acc[ii][0], acc[ii][1], acc[ii][2], acc[ii][3]};
        *(float4*)(out + (size_t)(m0 + ty * 2 + ii) * DHH + n0 + tx * 4) = r;
    }
}

// ---------------------------------------------------------------------------
extern "C" void kernel_launch(void* const* d_in, const int* in_sizes, int n_in,
                              void* d_out, int out_size, void* d_ws, size_t ws_size,
                              hipStream_t stream) {
    const float* x     = (const float*)d_in[0];
    const float* adj   = (const float*)d_in[1];
    const float* dense = (const float*)d_in[2];
    const float* Wq    = (const float*)d_in[3];
    const float* bq    = (const float*)d_in[4];
    const float* Wk    = (const float*)d_in[5];
    const float* bk    = (const float*)d_in[6];
    const float* Wv    = (const float*)d_in[7];
    const float* bv    = (const float*)d_in[8];
    const float* W1    = (const float*)d_in[9];
    const float* b1    = (const float*)d_in[10];
    const float* W2    = (const float*)d_in[11];
    const float* b2    = (const float*)d_in[12];
    const float* W3    = (const float*)d_in[13];
    const float* b3    = (const float*)d_in[14];
    float* out = (float*)d_out;
    float* ws  = (float*)d_ws;

    float* qm = ws;
    float* km = ws + 131072;
    float* vm = ws + 262144;
    float* sc = ws + 786432;

    hipLaunchKernelGGL(k_qkv,    dim3(32, 6),  dim3(256), 0, stream,
                       x, Wq, bq, Wk, bk, Wv, bv, qm, km, vm);
    hipLaunchKernelGGL(k_scores, dim3(32, 32), dim3(256), 0, stream, qm, km, sc);
    hipLaunchKernelGGL(k_mlp,    dim3(2048),   dim3(256), 0, stream,
                       sc, adj, dense, W1, b1, W2, b2, W3, b3);
    hipLaunchKernelGGL(k_feat,   dim3(4, 64),  dim3(256), 0, stream, sc, vm, out);
}

// Round 4
// 194.965 us; speedup vs baseline: 5.8425x; 1.3867x over previous
//
#include <hip/hip_runtime.h>
#include <math.h>

// N=2048, DH=256, DK=64, FF=32. fp32 in/out, f16 internal.
// ws layout (bytes):
//   q16  @ 0        : 2048x64   f16   (262144)
//   k16  @ 262144   : 2048x64   f16   (262144)
//   vT   @ 524288   : 256x2048  f16   (v transposed)      (1048576)
//   schi @ 1572864  : 2048x2048 f16   scores hi -> focus in place (8388608)
//   sclo @ 9961472  : 2048x2048 f16   scores lo           (8388608)
// total 18350080 B (~17.5 MB)  [< 19.9 MB proven available in R1]

#define NN  2048
#define DHH 256
#define DKK 64

typedef float    f32x4 __attribute__((ext_vector_type(4)));
typedef _Float16 f16x8 __attribute__((ext_vector_type(8)));
typedef _Float16 f16x4 __attribute__((ext_vector_type(4)));
typedef _Float16 f16x2 __attribute__((ext_vector_type(2)));

// 16-lane (DPP row) sum; result valid in lane 15 of each row-of-16. VALU pipe.
__device__ __forceinline__ float dpp_sum16(float x) {
    int v;
    v = __builtin_amdgcn_update_dpp(0, __builtin_bit_cast(int, x), 0x118, 0xf, 0xf, true);
    x += __builtin_bit_cast(float, v);
    v = __builtin_amdgcn_update_dpp(0, __builtin_bit_cast(int, x), 0x114, 0xf, 0xf, true);
    x += __builtin_bit_cast(float, v);
    v = __builtin_amdgcn_update_dpp(0, __builtin_bit_cast(int, x), 0x112, 0xf, 0xf, true);
    x += __builtin_bit_cast(float, v);
    v = __builtin_amdgcn_update_dpp(0, __builtin_bit_cast(int, x), 0x111, 0xf, 0xf, true);
    x += __builtin_bit_cast(float, v);
    return x;
}

// ---------------------------------------------------------------------------
// K1: qkv projections (fp32 math). q,k stored f16 row-major; v stored f16
// TRANSPOSED for k_feat's B-fragment reads.
// grid (32, 6): y=0 q, y=1 k, y=2..5 v col-groups.
// ---------------------------------------------------------------------------
__global__ __launch_bounds__(256) void k_qkv(
    const float* __restrict__ x,
    const float* __restrict__ Wq, const float* __restrict__ bq,
    const float* __restrict__ Wk, const float* __restrict__ bk,
    const float* __restrict__ Wv, const float* __restrict__ bv,
    _Float16* __restrict__ q16, _Float16* __restrict__ k16,
    _Float16* __restrict__ vT)
{
    __shared__ float As[32][64];
    __shared__ float Bs[32][64];
    __shared__ _Float16 Ts[64 * 72];   // transpose staging (pad 72)

    const int t  = threadIdx.x;
    const int m0 = blockIdx.x * 64;
    const int yb = blockIdx.y;

    const float* W; const float* bias; int wld; int cw0;
    if (yb == 0)      { W = Wq; bias = bq; wld = 64;  cw0 = 0; }
    else if (yb == 1) { W = Wk; bias = bk; wld = 64;  cw0 = 0; }
    else              { W = Wv; bias = bv; wld = 256; cw0 = (yb - 2) * 64; }

    const int tx = t & 15, ty = t >> 4;
    float acc[4][4] = {};

    for (int k0 = 0; k0 < DHH; k0 += 32) {
        {
            const int rr = t >> 3;
            const int cc = (t & 7) * 4;
            float4 a0 = *(const float4*)(x + (size_t)(m0 + rr)      * DHH + k0 + cc);
            float4 a1 = *(const float4*)(x + (size_t)(m0 + rr + 32) * DHH + k0 + cc);
            As[cc+0][rr]    = a0.x; As[cc+1][rr]    = a0.y; As[cc+2][rr]    = a0.z; As[cc+3][rr]    = a0.w;
            As[cc+0][rr+32] = a1.x; As[cc+1][rr+32] = a1.y; As[cc+2][rr+32] = a1.z; As[cc+3][rr+32] = a1.w;
        }
        {
            const int bk_ = t >> 4;
            const int bc  = (t & 15) * 4;
            *(float4*)&Bs[bk_][bc]      = *(const float4*)(W + (size_t)(k0 + bk_)      * wld + cw0 + bc);
            *(float4*)&Bs[bk_ + 16][bc] = *(const float4*)(W + (size_t)(k0 + bk_ + 16) * wld + cw0 + bc);
        }
        __syncthreads();
        #pragma unroll
        for (int kk = 0; kk < 32; ++kk) {
            float4 a = *(const float4*)&As[kk][ty * 4];
            float4 b = *(const float4*)&Bs[kk][tx * 4];
            float av[4] = {a.x, a.y, a.z, a.w};
            float bw[4] = {b.x, b.y, b.z, b.w};
            #pragma unroll
            for (int ii = 0; ii < 4; ++ii)
                #pragma unroll
                for (int jj = 0; jj < 4; ++jj)
                    acc[ii][jj] = fmaf(av[ii], bw[jj], acc[ii][jj]);
        }
        __syncthreads();
    }

    float4 b4 = *(const float4*)&bias[cw0 + tx * 4];
    float bc4[4] = {b4.x, b4.y, b4.z, b4.w};

    if (yb < 2) {
        _Float16* outp = (yb == 0) ? q16 : k16;
        #pragma unroll
        for (int ii = 0; ii < 4; ++ii) {
            f16x4 hv;
            #pragma unroll
            for (int jj = 0; jj < 4; ++jj) hv[jj] = (_Float16)(acc[ii][jj] + bc4[jj]);
            *(f16x4*)&outp[(size_t)(m0 + ty * 4 + ii) * 64 + tx * 4] = hv;
        }
    } else {
        // stage transposed tile: Ts[c*72 + m] = v[m0+m][cw0+c]
        #pragma unroll
        for (int jj = 0; jj < 4; ++jj) {
            f16x4 hv;
            #pragma unroll
            for (int ii = 0; ii < 4; ++ii) hv[ii] = (_Float16)(acc[ii][jj] + bc4[jj]);
            *(f16x4*)&Ts[(tx * 4 + jj) * 72 + ty * 4] = hv;
        }
        __syncthreads();
        // writeback: each thread moves 16 halves -> full 64x64 coverage
        {
            const int c = t >> 2, seg = t & 3;
            f16x8 r0 = *(const f16x8*)&Ts[c * 72 + seg * 16];
            f16x8 r1 = *(const f16x8*)&Ts[c * 72 + seg * 16 + 8];
            *(f16x8*)&vT[(size_t)(cw0 + c) * NN + m0 + seg * 16]     = r0;
            *(f16x8*)&vT[(size_t)(cw0 + c) * NN + m0 + seg * 16 + 8] = r1;
        }
    }
}

// ---------------------------------------------------------------------------
// K2: scores = k16 @ q16^T via f16 MFMA, no LDS. Block 128x128, 4 waves each
// 64x64. Stores hi/lo f16 split of each score.
// ---------------------------------------------------------------------------
__global__ __launch_bounds__(256) void k_scores(
    const _Float16* __restrict__ q16, const _Float16* __restrict__ k16,
    _Float16* __restrict__ schi, _Float16* __restrict__ sclo)
{
    const int t    = threadIdx.x;
    const int lane = t & 63;
    const int w    = t >> 6;
    const int col  = lane & 15;
    const int q    = lane >> 4;

    const int i0 = blockIdx.y * 128 + (w >> 1) * 64;
    const int j0 = blockIdx.x * 128 + (w & 1) * 64;

    f32x4 acc[4][4] = {};

    #pragma unroll
    for (int ks = 0; ks < 2; ++ks) {
        f16x8 a[4], b[4];
        #pragma unroll
        for (int f = 0; f < 4; ++f) {
            a[f] = *(const f16x8*)&k16[(size_t)(i0 + f * 16 + col) * 64 + ks * 32 + q * 8];
            b[f] = *(const f16x8*)&q16[(size_t)(j0 + f * 16 + col) * 64 + ks * 32 + q * 8];
        }
        #pragma unroll
        for (int fm = 0; fm < 4; ++fm)
            #pragma unroll
            for (int fn = 0; fn < 4; ++fn)
                acc[fm][fn] = __builtin_amdgcn_mfma_f32_16x16x32_f16(a[fm], b[fn], acc[fm][fn], 0, 0, 0);
    }

    #pragma unroll
    for (int fm = 0; fm < 4; ++fm)
        #pragma unroll
        for (int fn = 0; fn < 4; ++fn)
            #pragma unroll
            for (int r = 0; r < 4; ++r) {
                const size_t idx = (size_t)(i0 + fm * 16 + q * 4 + r) * NN + j0 + fn * 16 + col;
                const float val = acc[fm][fn][r];
                const _Float16 h = (_Float16)val;
                schi[idx] = h;
                sclo[idx] = (_Float16)(val - (float)h);
            }
}

// ---------------------------------------------------------------------------
// K3: per-edge MLP + row softmax. One block per row, 4 independent waves
// (no main-loop barriers). Layer1+2 on MFMA, layer-3 reduce on DPP (VALU).
// Layer-1 A slots: {s_hi, s_lo, a, d, s_hi, 0,0,0} paired with B rows
// {W1_0hi, W1_0hi, W1_1, W1_2, W1_0lo} -> s enters layer 1 at ~fp32.
// Writes focus (f16) in-place over schi.
// ---------------------------------------------------------------------------
__global__ __launch_bounds__(256) void k_mlp(
    const _Float16* __restrict__ schi, const _Float16* __restrict__ sclo,
    const float* __restrict__ adj, const float* __restrict__ dense,
    const float* __restrict__ W1, const float* __restrict__ b1,
    const float* __restrict__ W2, const float* __restrict__ b2,
    const float* __restrict__ W3, const float* __restrict__ b3,
    _Float16* __restrict__ fhi)
{
    __shared__ _Float16 fA[4][64 * 8];    // per-wave feats, A-layout rows (16B each)
    __shared__ _Float16 hs[4][64 * 40];   // per-wave h staging, stride 40 halves
    __shared__ _Float16 zsh[8];           // zero A-frag for q>0 lanes
    __shared__ float    lsg[NN];
    __shared__ float    red[8];

    const int t    = threadIdx.x;
    const int lane = t & 63;
    const int w    = t >> 6;
    const int col  = lane & 15;
    const int q    = lane >> 4;
    const int i    = blockIdx.x;

    if (t < 8) zsh[t] = (_Float16)0;
    __syncthreads();

    // loop-invariant fragments
    f16x8 w1f0 = {}, w1f1 = {};
    if (q == 0) {
        const int ne = 2 * col, no = 2 * col + 1;
        const float w0e = W1[0*32 + ne], w0o = W1[0*32 + no];
        const _Float16 w0eh = (_Float16)w0e, w0oh = (_Float16)w0o;
        w1f0[0] = w0eh; w1f0[1] = w0eh;
        w1f0[2] = (_Float16)W1[1*32 + ne];
        w1f0[3] = (_Float16)W1[2*32 + ne];
        w1f0[4] = (_Float16)(w0e - (float)w0eh);
        w1f1[0] = w0oh; w1f1[1] = w0oh;
        w1f1[2] = (_Float16)W1[1*32 + no];
        w1f1[3] = (_Float16)W1[2*32 + no];
        w1f1[4] = (_Float16)(w0o - (float)w0oh);
    }
    f16x8 w2f0, w2f1;
    #pragma unroll
    for (int j = 0; j < 8; ++j) {
        w2f0[j] = (_Float16)W2[(q * 8 + j) * 32 + col];
        w2f1[j] = (_Float16)W2[(q * 8 + j) * 32 + col + 16];
    }
    const float b1e = b1[2 * col], b1o = b1[2 * col + 1];
    const float b2a = b2[col],     b2b = b2[col + 16];
    const float w3a = W3[col],     w3b = W3[col + 16];
    const float b3v = b3[0];

    const _Float16* shrow = schi + (size_t)i * NN;
    const _Float16* slrow = sclo + (size_t)i * NN;
    const float*    arow  = adj   + (size_t)i * NN;
    const float*    drow  = dense + (size_t)i * NN;

    const f32x4 zero4 = {0.f, 0.f, 0.f, 0.f};

    for (int c = 0; c < 8; ++c) {
        const int base = w * 512 + c * 64;
        const int jj   = base + lane;

        // stage this lane's edge feats (single 16B ds_write, tail zeros)
        {
            const _Float16 sh = shrow[jj];
            const _Float16 sl = slrow[jj];
            f16x8 fv = {sh, sl, (_Float16)arow[jj], (_Float16)drow[jj],
                        sh, (_Float16)0, (_Float16)0, (_Float16)0};
            *(f16x8*)&fA[w][lane * 8] = fv;
        }
        asm volatile("s_waitcnt lgkmcnt(0)" ::: "memory");

        // ---- layer 1 ----
        #pragma unroll
        for (int st = 0; st < 4; ++st) {
            const _Float16* ap = (q == 0) ? &fA[w][(st * 16 + col) * 8] : zsh;
            f16x8 af = *(const f16x8*)ap;
            f32x4 hp0 = __builtin_amdgcn_mfma_f32_16x16x32_f16(af, w1f0, zero4, 0, 0, 0);
            f32x4 hp1 = __builtin_amdgcn_mfma_f32_16x16x32_f16(af, w1f1, zero4, 0, 0, 0);
            #pragma unroll
            for (int r = 0; r < 4; ++r) {
                f16x2 pk;
                pk[0] = (_Float16)fmaxf(hp0[r] + b1e, 0.f);
                pk[1] = (_Float16)fmaxf(hp1[r] + b1o, 0.f);
                *(f16x2*)&hs[w][(st * 16 + q * 4 + r) * 40 + col * 2] = pk;
            }
        }
        asm volatile("s_waitcnt lgkmcnt(0)" ::: "memory");

        // ---- layer 2 + 3 ----
        #pragma unroll
        for (int st = 0; st < 4; ++st) {
            f16x8 a2 = *(const f16x8*)&hs[w][(st * 16 + col) * 40 + q * 8];
            f32x4 acc0 = __builtin_amdgcn_mfma_f32_16x16x32_f16(a2, w2f0, zero4, 0, 0, 0);
            f32x4 acc1 = __builtin_amdgcn_mfma_f32_16x16x32_f16(a2, w2f1, zero4, 0, 0, 0);
            float p[4];
            #pragma unroll
            for (int r = 0; r < 4; ++r) {
                p[r] = fmaxf(acc0[r] + b2a, 0.f) * w3a + fmaxf(acc1[r] + b2b, 0.f) * w3b;
                p[r] = dpp_sum16(p[r]);
            }
            if (col == 15) {
                float4 lgv = {p[0] + b3v, p[1] + b3v, p[2] + b3v, p[3] + b3v};
                *(float4*)&lsg[base + st * 16 + q * 4] = lgv;
            }
        }
        asm volatile("s_waitcnt lgkmcnt(0)" ::: "memory");
    }
    __syncthreads();

    // ---- row softmax ----
    float lv[8], lmax = -1e30f;
    #pragma unroll
    for (int u = 0; u < 8; ++u) { lv[u] = lsg[t + u * 256]; lmax = fmaxf(lmax, lv[u]); }
    #pragma unroll
    for (int off = 32; off > 0; off >>= 1)
        lmax = fmaxf(lmax, __shfl_xor(lmax, off, 64));
    if (lane == 0) red[w] = lmax;
    __syncthreads();
    const float rmax = fmaxf(fmaxf(red[0], red[1]), fmaxf(red[2], red[3]));

    float wgt[8], lsum = 0.f;
    #pragma unroll
    for (int u = 0; u < 8; ++u) { wgt[u] = __expf(lv[u] - rmax); lsum += wgt[u]; }
    #pragma unroll
    for (int off = 32; off > 0; off >>= 1)
        lsum += __shfl_xor(lsum, off, 64);
    if (lane == 0) red[4 + w] = lsum;
    __syncthreads();
    const float inv = 1.f / (red[4] + red[5] + red[6] + red[7]);

    _Float16* hrow = fhi + (size_t)i * NN;
    #pragma unroll
    for (int u = 0; u < 8; ++u)
        hrow[t + u * 256] = (_Float16)(wgt[u] * inv);
}

// ---------------------------------------------------------------------------
// K4: feature = focus @ v via f16 MFMA (focus f16, vT f16 — error ~2e-5).
// grid (2,128): block = 16 rows x 128 cols; wave w owns 32 cols (2 n-frags).
// ---------------------------------------------------------------------------
__global__ __launch_bounds__(256) void k_feat(
    const _Float16* __restrict__ fhi, const _Float16* __restrict__ vT,
    float* __restrict__ out)
{
    const int t    = threadIdx.x;
    const int lane = t & 63;
    const int w    = t >> 6;
    const int col  = lane & 15;
    const int q    = lane >> 4;

    const int m0 = blockIdx.y * 16;
    const int n0 = blockIdx.x * 128 + w * 32;

    f32x4 acc[2] = {};

    const size_t arow  = (size_t)(m0 + col) * NN;
    const size_t brow0 = (size_t)(n0 + col) * NN;
    const size_t brow1 = (size_t)(n0 + 16 + col) * NN;

    for (int k0 = 0; k0 < NN; k0 += 32) {
        const int ko = k0 + q * 8;
        f16x8 a  = *(const f16x8*)&fhi[arow + ko];
        f16x8 b0 = *(const f16x8*)&vT[brow0 + ko];
        f16x8 b1 = *(const f16x8*)&vT[brow1 + ko];
        acc[0] = __builtin_amdgcn_mfma_f32_16x16x32_f16(a, b0, acc[0], 0, 0, 0);
        acc[1] = __builtin_amdgcn_mfma_f32_16x16x32_f16(a, b1, acc[1], 0, 0, 0);
    }

    #pragma unroll
    for (int fn = 0; fn < 2; ++fn)
        #pragma unroll
        for (int r = 0; r < 4; ++r)
            out[(size_t)(m0 + q * 4 + r) * DHH + n0 + fn * 16 + col] = acc[fn][r];
}

// ---------------------------------------------------------------------------
extern "C" void kernel_launch(void* const* d_in, const int* in_sizes, int n_in,
                              void* d_out, int out_size, void* d_ws, size_t ws_size,
                              hipStream_t stream) {
    const float* x     = (const float*)d_in[0];
    const float* adj   = (const float*)d_in[1];
    const float* dense = (const float*)d_in[2];
    const float* Wq    = (const float*)d_in[3];
    const float* bq    = (const float*)d_in[4];
    const float* Wk    = (const float*)d_in[5];
    const float* bk    = (const float*)d_in[6];
    const float* Wv    = (const float*)d_in[7];
    const float* bv    = (const float*)d_in[8];
    const float* W1    = (const float*)d_in[9];
    const float* b1    = (const float*)d_in[10];
    const float* W2    = (const float*)d_in[11];
    const float* b2    = (const float*)d_in[12];
    const float* W3    = (const float*)d_in[13];
    const float* b3    = (const float*)d_in[14];
    float* out = (float*)d_out;

    char* wsb = (char*)d_ws;
    _Float16* q16  = (_Float16*)(wsb);
    _Float16* k16  = (_Float16*)(wsb + 262144);
    _Float16* vT   = (_Float16*)(wsb + 524288);
    _Float16* schi = (_Float16*)(wsb + 1572864);   // scores hi, then focus in place
    _Float16* sclo = (_Float16*)(wsb + 9961472);   // scores lo

    hipLaunchKernelGGL(k_qkv,    dim3(32, 6),  dim3(256), 0, stream,
                       x, Wq, bq, Wk, bk, Wv, bv, q16, k16, vT);
    hipLaunchKernelGGL(k_scores, dim3(16, 16), dim3(256), 0, stream, q16, k16, schi, sclo);
    hipLaunchKernelGGL(k_mlp,    dim3(2048),   dim3(256), 0, stream,
                       schi, sclo, adj, dense, W1, b1, W2, b2, W3, b3, schi);
    hipLaunchKernelGGL(k_feat,   dim3(2, 128), dim3(256), 0, stream,
                       schi, vT, out);
}

// Round 6
// 183.843 us; speedup vs baseline: 6.1960x; 1.0605x over previous
//
#include <hip/hip_runtime.h>
#include <math.h>

// N=2048, DH=256, DK=64, FF=32. fp32 in/out, f16 internal.
// ws layout (bytes):
//   q16  @ 0        : 2048x64   f16   (262144)
//   k16  @ 262144   : 2048x64   f16   (262144)
//   vT   @ 524288   : 256x2048  f16   (v transposed)      (1048576)
//   schi @ 1572864  : 2048x2048 f16   scores hi -> focus in place (8388608)
//   sclo @ 9961472  : 2048x2048 f16   scores lo           (8388608)

#define NN  2048
#define DHH 256
#define DKK 64

typedef float    f32x4 __attribute__((ext_vector_type(4)));
typedef _Float16 f16x8 __attribute__((ext_vector_type(8)));
typedef _Float16 f16x4 __attribute__((ext_vector_type(4)));
typedef _Float16 f16x2 __attribute__((ext_vector_type(2)));

// ---------------------------------------------------------------------------
// K1: qkv projections (fp32 math). q,k stored f16 row-major; v stored f16
// transposed. grid (32, 6): y=0 q, y=1 k, y=2..5 v col-groups.
// ---------------------------------------------------------------------------
__global__ __launch_bounds__(256) void k_qkv(
    const float* __restrict__ x,
    const float* __restrict__ Wq, const float* __restrict__ bq,
    const float* __restrict__ Wk, const float* __restrict__ bk,
    const float* __restrict__ Wv, const float* __restrict__ bv,
    _Float16* __restrict__ q16, _Float16* __restrict__ k16,
    _Float16* __restrict__ vT)
{
    __shared__ float As[32][64];
    __shared__ float Bs[32][64];
    __shared__ _Float16 Ts[64 * 72];

    const int t  = threadIdx.x;
    const int m0 = blockIdx.x * 64;
    const int yb = blockIdx.y;

    const float* W; const float* bias; int wld; int cw0;
    if (yb == 0)      { W = Wq; bias = bq; wld = 64;  cw0 = 0; }
    else if (yb == 1) { W = Wk; bias = bk; wld = 64;  cw0 = 0; }
    else              { W = Wv; bias = bv; wld = 256; cw0 = (yb - 2) * 64; }

    const int tx = t & 15, ty = t >> 4;
    float acc[4][4] = {};

    for (int k0 = 0; k0 < DHH; k0 += 32) {
        {
            const int rr = t >> 3;
            const int cc = (t & 7) * 4;
            float4 a0 = *(const float4*)(x + (size_t)(m0 + rr)      * DHH + k0 + cc);
            float4 a1 = *(const float4*)(x + (size_t)(m0 + rr + 32) * DHH + k0 + cc);
            As[cc+0][rr]    = a0.x; As[cc+1][rr]    = a0.y; As[cc+2][rr]    = a0.z; As[cc+3][rr]    = a0.w;
            As[cc+0][rr+32] = a1.x; As[cc+1][rr+32] = a1.y; As[cc+2][rr+32] = a1.z; As[cc+3][rr+32] = a1.w;
        }
        {
            const int bk_ = t >> 4;
            const int bc  = (t & 15) * 4;
            *(float4*)&Bs[bk_][bc]      = *(const float4*)(W + (size_t)(k0 + bk_)      * wld + cw0 + bc);
            *(float4*)&Bs[bk_ + 16][bc] = *(const float4*)(W + (size_t)(k0 + bk_ + 16) * wld + cw0 + bc);
        }
        __syncthreads();
        #pragma unroll
        for (int kk = 0; kk < 32; ++kk) {
            float4 a = *(const float4*)&As[kk][ty * 4];
            float4 b = *(const float4*)&Bs[kk][tx * 4];
            float av[4] = {a.x, a.y, a.z, a.w};
            float bw[4] = {b.x, b.y, b.z, b.w};
            #pragma unroll
            for (int ii = 0; ii < 4; ++ii)
                #pragma unroll
                for (int jj = 0; jj < 4; ++jj)
                    acc[ii][jj] = fmaf(av[ii], bw[jj], acc[ii][jj]);
        }
        __syncthreads();
    }

    float4 b4 = *(const float4*)&bias[cw0 + tx * 4];
    float bc4[4] = {b4.x, b4.y, b4.z, b4.w};

    if (yb < 2) {
        _Float16* outp = (yb == 0) ? q16 : k16;
        #pragma unroll
        for (int ii = 0; ii < 4; ++ii) {
            f16x4 hv;
            #pragma unroll
            for (int jj = 0; jj < 4; ++jj) hv[jj] = (_Float16)(acc[ii][jj] + bc4[jj]);
            *(f16x4*)&outp[(size_t)(m0 + ty * 4 + ii) * 64 + tx * 4] = hv;
        }
    } else {
        #pragma unroll
        for (int jj = 0; jj < 4; ++jj) {
            f16x4 hv;
            #pragma unroll
            for (int ii = 0; ii < 4; ++ii) hv[ii] = (_Float16)(acc[ii][jj] + bc4[jj]);
            *(f16x4*)&Ts[(tx * 4 + jj) * 72 + ty * 4] = hv;
        }
        __syncthreads();
        {
            const int c = t >> 2, seg = t & 3;
            f16x8 r0 = *(const f16x8*)&Ts[c * 72 + seg * 16];
            f16x8 r1 = *(const f16x8*)&Ts[c * 72 + seg * 16 + 8];
            *(f16x8*)&vT[(size_t)(cw0 + c) * NN + m0 + seg * 16]     = r0;
            *(f16x8*)&vT[(size_t)(cw0 + c) * NN + m0 + seg * 16 + 8] = r1;
        }
    }
}

// ---------------------------------------------------------------------------
// K2: scores = k16 @ q16^T via f16 MFMA, no LDS. 128x128 per block, 4 waves.
// Stores hi/lo f16 split.
// ---------------------------------------------------------------------------
__global__ __launch_bounds__(256) void k_scores(
    const _Float16* __restrict__ q16, const _Float16* __restrict__ k16,
    _Float16* __restrict__ schi, _Float16* __restrict__ sclo)
{
    const int t    = threadIdx.x;
    const int lane = t & 63;
    const int w    = t >> 6;
    const int col  = lane & 15;
    const int q    = lane >> 4;

    const int i0 = blockIdx.y * 128 + (w >> 1) * 64;
    const int j0 = blockIdx.x * 128 + (w & 1) * 64;

    f32x4 acc[4][4] = {};

    #pragma unroll
    for (int ks = 0; ks < 2; ++ks) {
        f16x8 a[4], b[4];
        #pragma unroll
        for (int f = 0; f < 4; ++f) {
            a[f] = *(const f16x8*)&k16[(size_t)(i0 + f * 16 + col) * 64 + ks * 32 + q * 8];
            b[f] = *(const f16x8*)&q16[(size_t)(j0 + f * 16 + col) * 64 + ks * 32 + q * 8];
        }
        #pragma unroll
        for (int fm = 0; fm < 4; ++fm)
            #pragma unroll
            for (int fn = 0; fn < 4; ++fn)
                acc[fm][fn] = __builtin_amdgcn_mfma_f32_16x16x32_f16(a[fm], b[fn], acc[fm][fn], 0, 0, 0);
    }

    #pragma unroll
    for (int fm = 0; fm < 4; ++fm)
        #pragma unroll
        for (int fn = 0; fn < 4; ++fn)
            #pragma unroll
            for (int r = 0; r < 4; ++r) {
                const size_t idx = (size_t)(i0 + fm * 16 + q * 4 + r) * NN + j0 + fn * 16 + col;
                const float val = acc[fm][fn][r];
                const _Float16 h = (_Float16)val;
                schi[idx] = h;
                sclo[idx] = (_Float16)(val - (float)h);
            }
}

// ---------------------------------------------------------------------------
// K3: per-edge MLP + row softmax. One block per row, 4 barrier-free waves.
// b1/b2 folded into MFMA C-init; layer-2 operand-swapped so featout is on the
// row axis -> layer-3 W3-dot is 8 per-lane fma + 2 shfl_xor; b3 cancels in
// softmax; hs shrunk to 16 rows/wave (LDS 33->~17 KB, 2x occupancy).
// ---------------------------------------------------------------------------
__global__ __launch_bounds__(256) void k_mlp(
    const _Float16* __restrict__ schi, const _Float16* __restrict__ sclo,
    const float* __restrict__ adj, const float* __restrict__ dense,
    const float* __restrict__ W1, const float* __restrict__ b1,
    const float* __restrict__ W2, const float* __restrict__ b2,
    const float* __restrict__ W3,
    _Float16* __restrict__ fhi)
{
    __shared__ _Float16 fA[4][64 * 8];    // per-wave feats, A-layout rows
    __shared__ _Float16 hs[4][16 * 40];   // per-wave 16-row h staging
    __shared__ _Float16 zsh[8];
    __shared__ float    lsg[NN];
    __shared__ float    red[8];

    const int t    = threadIdx.x;
    const int lane = t & 63;
    const int w    = t >> 6;
    const int col  = lane & 15;
    const int q    = lane >> 4;
    const int i    = blockIdx.x;

    if (t < 8) zsh[t] = (_Float16)0;
    __syncthreads();

    // loop-invariant fragments
    f16x8 w1f0 = {}, w1f1 = {};
    if (q == 0) {
        const int ne = 2 * col, no = 2 * col + 1;
        const float w0e = W1[0*32 + ne], w0o = W1[0*32 + no];
        const _Float16 w0eh = (_Float16)w0e, w0oh = (_Float16)w0o;
        w1f0[0] = w0eh; w1f0[1] = w0eh;
        w1f0[2] = (_Float16)W1[1*32 + ne];
        w1f0[3] = (_Float16)W1[2*32 + ne];
        w1f0[4] = (_Float16)(w0e - (float)w0eh);
        w1f1[0] = w0oh; w1f1[1] = w0oh;
        w1f1[2] = (_Float16)W1[1*32 + no];
        w1f1[3] = (_Float16)W1[2*32 + no];
        w1f1[4] = (_Float16)(w0o - (float)w0oh);
    }
    f16x8 w2f0, w2f1;
    #pragma unroll
    for (int j = 0; j < 8; ++j) {
        w2f0[j] = (_Float16)W2[(q * 8 + j) * 32 + col];
        w2f1[j] = (_Float16)W2[(q * 8 + j) * 32 + col + 16];
    }
    const float b1e = b1[2 * col], b1o = b1[2 * col + 1];
    const f32x4 c1e = {b1e, b1e, b1e, b1e};
    const f32x4 c1o = {b1o, b1o, b1o, b1o};
    f32x4 c2a, c2b, w3v, w3v2;
    #pragma unroll
    for (int r = 0; r < 4; ++r) {
        c2a[r]  = b2[q * 4 + r];
        c2b[r]  = b2[16 + q * 4 + r];
        w3v[r]  = W3[q * 4 + r];
        w3v2[r] = W3[16 + q * 4 + r];
    }

    const _Float16* shrow = schi + (size_t)i * NN;
    const _Float16* slrow = sclo + (size_t)i * NN;
    const float*    arow  = adj   + (size_t)i * NN;
    const float*    drow  = dense + (size_t)i * NN;

    for (int c = 0; c < 8; ++c) {
        const int base = w * 512 + c * 64;
        const int jj   = base + lane;

        // stage this lane's edge feats (single 16B ds_write)
        {
            f16x8 fv = {shrow[jj], slrow[jj], (_Float16)arow[jj], (_Float16)drow[jj],
                        shrow[jj], (_Float16)0, (_Float16)0, (_Float16)0};
            *(f16x8*)&fA[w][lane * 8] = fv;
        }
        asm volatile("s_waitcnt lgkmcnt(0)" ::: "memory");

        #pragma unroll
        for (int st = 0; st < 4; ++st) {
            // ---- layer 1 (bias via C-init) ----
            const _Float16* ap = (q == 0) ? &fA[w][(st * 16 + col) * 8] : zsh;
            f16x8 af = *(const f16x8*)ap;
            f32x4 hp0 = __builtin_amdgcn_mfma_f32_16x16x32_f16(af, w1f0, c1e, 0, 0, 0);
            f32x4 hp1 = __builtin_amdgcn_mfma_f32_16x16x32_f16(af, w1f1, c1o, 0, 0, 0);
            #pragma unroll
            for (int r = 0; r < 4; ++r) {
                f16x2 pk = __builtin_bit_cast(f16x2,
                    __builtin_amdgcn_cvt_pkrtz(fmaxf(hp0[r], 0.f), fmaxf(hp1[r], 0.f)));
                *(f16x2*)&hs[w][(q * 4 + r) * 40 + col * 2] = pk;
            }
            asm volatile("s_waitcnt lgkmcnt(0)" ::: "memory");

            // ---- layer 2 (operand-swapped: C[featout][edge]) + layer 3 ----
            f16x8 a2 = *(const f16x8*)&hs[w][col * 40 + q * 8];
            f32x4 acc0 = __builtin_amdgcn_mfma_f32_16x16x32_f16(w2f0, a2, c2a, 0, 0, 0);
            f32x4 acc1 = __builtin_amdgcn_mfma_f32_16x16x32_f16(w2f1, a2, c2b, 0, 0, 0);
            float p = 0.f;
            #pragma unroll
            for (int r = 0; r < 4; ++r) {
                p = fmaf(fmaxf(acc0[r], 0.f), w3v[r],  p);
                p = fmaf(fmaxf(acc1[r], 0.f), w3v2[r], p);
            }
            p += __shfl_xor(p, 16, 64);
            p += __shfl_xor(p, 32, 64);
            if (q == st) lsg[base + st * 16 + col] = p;
            asm volatile("s_waitcnt lgkmcnt(0)" ::: "memory");  // hs WAR for next st
        }
    }
    __syncthreads();

    // ---- row softmax ----
    float lv[8], lmax = -1e30f;
    #pragma unroll
    for (int u = 0; u < 8; ++u) { lv[u] = lsg[t + u * 256]; lmax = fmaxf(lmax, lv[u]); }
    #pragma unroll
    for (int off = 32; off > 0; off >>= 1)
        lmax = fmaxf(lmax, __shfl_xor(lmax, off, 64));
    if (lane == 0) red[w] = lmax;
    __syncthreads();
    const float rmax = fmaxf(fmaxf(red[0], red[1]), fmaxf(red[2], red[3]));

    float wgt[8], lsum = 0.f;
    #pragma unroll
    for (int u = 0; u < 8; ++u) { wgt[u] = __expf(lv[u] - rmax); lsum += wgt[u]; }
    #pragma unroll
    for (int off = 32; off > 0; off >>= 1)
        lsum += __shfl_xor(lsum, off, 64);
    if (lane == 0) red[4 + w] = lsum;
    __syncthreads();
    const float inv = 1.f / (red[4] + red[5] + red[6] + red[7]);

    _Float16* hrow = fhi + (size_t)i * NN;
    #pragma unroll
    for (int u = 0; u < 8; ++u)
        hrow[t + u * 256] = (_Float16)(wgt[u] * inv);
}

// ---------------------------------------------------------------------------
// K4: feature = focus @ v via f16 MFMA, K split 4-way across waves + LDS
// reduce. grid (8,128): tile 16 rows x 32 cols; 1024 blocks -> 16 waves/CU.
// ---------------------------------------------------------------------------
__global__ __launch_bounds__(256) void k_feat(
    const _Float16* __restrict__ fhi, const _Float16* __restrict__ vT,
    float* __restrict__ out)
{
    __shared__ float rbuf[3][64][8];

    const int t    = threadIdx.x;
    const int lane = t & 63;
    const int w    = t >> 6;
    const int col  = lane & 15;
    const int q    = lane >> 4;

    const int m0 = blockIdx.y * 16;
    const int n0 = blockIdx.x * 32;

    f32x4 acc0 = {}, acc1 = {};

    const size_t arow  = (size_t)(m0 + col) * NN;
    const size_t brow0 = (size_t)(n0 + col) * NN;
    const size_t brow1 = (size_t)(n0 + 16 + col) * NN;
    const int kb = w * 512 + q * 8;

    #pragma unroll 4
    for (int k0 = 0; k0 < 512; k0 += 32) {
        const int ko = kb + k0;
        f16x8 a  = *(const f16x8*)&fhi[arow + ko];
        f16x8 b0 = *(const f16x8*)&vT[brow0 + ko];
        f16x8 b1 = *(const f16x8*)&vT[brow1 + ko];
        acc0 = __builtin_amdgcn_mfma_f32_16x16x32_f16(a, b0, acc0, 0, 0, 0);
        acc1 = __builtin_amdgcn_mfma_f32_16x16x32_f16(a, b1, acc1, 0, 0, 0);
    }

    if (w != 0) {
        *(float4*)&rbuf[w - 1][lane][0] = *(float4*)&acc0;
        *(float4*)&rbuf[w - 1][lane][4] = *(float4*)&acc1;
    }
    __syncthreads();

    if (w == 0) {
        #pragma unroll
        for (int j = 0; j < 3; ++j) {
            float4 p0 = *(const float4*)&rbuf[j][lane][0];
            float4 p1 = *(const float4*)&rbuf[j][lane][4];
            acc0[0] += p0.x; acc0[1] += p0.y; acc0[2] += p0.z; acc0[3] += p0.w;
            acc1[0] += p1.x; acc1[1] += p1.y; acc1[2] += p1.z; acc1[3] += p1.w;
        }
        #pragma unroll
        for (int r = 0; r < 4; ++r) {
            out[(size_t)(m0 + q * 4 + r) * DHH + n0 + col]      = acc0[r];
            out[(size_t)(m0 + q * 4 + r) * DHH + n0 + 16 + col] = acc1[r];
        }
    }
}

// ---------------------------------------------------------------------------
extern "C" void kernel_launch(void* const* d_in, const int* in_sizes, int n_in,
                              void* d_out, int out_size, void* d_ws, size_t ws_size,
                              hipStream_t stream) {
    const float* x     = (const float*)d_in[0];
    const float* adj   = (const float*)d_in[1];
    const float* dense = (const float*)d_in[2];
    const float* Wq    = (const float*)d_in[3];
    const float* bq    = (const float*)d_in[4];
    const float* Wk    = (const float*)d_in[5];
    const float* bk    = (const float*)d_in[6];
    const float* Wv    = (const float*)d_in[7];
    const float* bv    = (const float*)d_in[8];
    const float* W1    = (const float*)d_in[9];
    const float* b1    = (const float*)d_in[10];
    const float* W2    = (const float*)d_in[11];
    const float* b2    = (const float*)d_in[12];
    const float* W3    = (const float*)d_in[13];
    float* out = (float*)d_out;

    char* wsb = (char*)d_ws;
    _Float16* q16  = (_Float16*)(wsb);
    _Float16* k16  = (_Float16*)(wsb + 262144);
    _Float16* vT   = (_Float16*)(wsb + 524288);
    _Float16* schi = (_Float16*)(wsb + 1572864);
    _Float16* sclo = (_Float16*)(wsb + 9961472);

    hipLaunchKernelGGL(k_qkv,    dim3(32, 6),  dim3(256), 0, stream,
                       x, Wq, bq, Wk, bk, Wv, bv, q16, k16, vT);
    hipLaunchKernelGGL(k_scores, dim3(16, 16), dim3(256), 0, stream, q16, k16, schi, sclo);
    hipLaunchKernelGGL(k_mlp,    dim3(2048),   dim3(256), 0, stream,
                       schi, sclo, adj, dense, W1, b1, W2, b2, W3, schi);
    hipLaunchKernelGGL(k_feat,   dim3(8, 128), dim3(256), 0, stream,
                       schi, vT, out);
}

// Round 8
// 183.639 us; speedup vs baseline: 6.2028x; 1.0011x over previous
//
#include <hip/hip_runtime.h>
#include <math.h>

// N=2048, DH=256, DK=64, FF=32. fp32 in/out, f16 internal.
// ws layout (bytes):
//   q16  @ 0        : 2048x64   f16    (262144)
//   k16  @ 262144   : 2048x64   f16    (262144)
//   vT   @ 524288   : 256x2048  f16    (v transposed)  (1048576)
//   schl @ 1572864  : 2048x2048 f16x2  packed (score_hi, score_lo) (16777216)
//     -> focus (f16, contiguous 2048) overwrites the first half of each
//        schl row in-place; k_feat reads it with row stride 2*NN halves.

#define NN  2048
#define DHH 256
#define DKK 64

typedef float    f32x4 __attribute__((ext_vector_type(4)));
typedef _Float16 f16x8 __attribute__((ext_vector_type(8)));
typedef _Float16 f16x4 __attribute__((ext_vector_type(4)));
typedef _Float16 f16x2 __attribute__((ext_vector_type(2)));
typedef int      i32x4 __attribute__((ext_vector_type(4)));

// ---------------------------------------------------------------------------
// K1: qkv projections (fp32 math). q,k stored f16 row-major; v stored f16
// transposed. grid (32, 6): y=0 q, y=1 k, y=2..5 v col-groups.
// ---------------------------------------------------------------------------
__global__ __launch_bounds__(256) void k_qkv(
    const float* __restrict__ x,
    const float* __restrict__ Wq, const float* __restrict__ bq,
    const float* __restrict__ Wk, const float* __restrict__ bk,
    const float* __restrict__ Wv, const float* __restrict__ bv,
    _Float16* __restrict__ q16, _Float16* __restrict__ k16,
    _Float16* __restrict__ vT)
{
    __shared__ float As[32][64];
    __shared__ float Bs[32][64];
    __shared__ _Float16 Ts[64 * 72];

    const int t  = threadIdx.x;
    const int m0 = blockIdx.x * 64;
    const int yb = blockIdx.y;

    const float* W; const float* bias; int wld; int cw0;
    if (yb == 0)      { W = Wq; bias = bq; wld = 64;  cw0 = 0; }
    else if (yb == 1) { W = Wk; bias = bk; wld = 64;  cw0 = 0; }
    else              { W = Wv; bias = bv; wld = 256; cw0 = (yb - 2) * 64; }

    const int tx = t & 15, ty = t >> 4;
    float acc[4][4] = {};

    for (int k0 = 0; k0 < DHH; k0 += 32) {
        {
            const int rr = t >> 3;
            const int cc = (t & 7) * 4;
            float4 a0 = *(const float4*)(x + (size_t)(m0 + rr)      * DHH + k0 + cc);
            float4 a1 = *(const float4*)(x + (size_t)(m0 + rr + 32) * DHH + k0 + cc);
            As[cc+0][rr]    = a0.x; As[cc+1][rr]    = a0.y; As[cc+2][rr]    = a0.z; As[cc+3][rr]    = a0.w;
            As[cc+0][rr+32] = a1.x; As[cc+1][rr+32] = a1.y; As[cc+2][rr+32] = a1.z; As[cc+3][rr+32] = a1.w;
        }
        {
            const int bk_ = t >> 4;
            const int bc  = (t & 15) * 4;
            *(float4*)&Bs[bk_][bc]      = *(const float4*)(W + (size_t)(k0 + bk_)      * wld + cw0 + bc);
            *(float4*)&Bs[bk_ + 16][bc] = *(const float4*)(W + (size_t)(k0 + bk_ + 16) * wld + cw0 + bc);
        }
        __syncthreads();
        #pragma unroll
        for (int kk = 0; kk < 32; ++kk) {
            float4 a = *(const float4*)&As[kk][ty * 4];
            float4 b = *(const float4*)&Bs[kk][tx * 4];
            float av[4] = {a.x, a.y, a.z, a.w};
            float bw[4] = {b.x, b.y, b.z, b.w};
            #pragma unroll
            for (int ii = 0; ii < 4; ++ii)
                #pragma unroll
                for (int jj = 0; jj < 4; ++jj)
                    acc[ii][jj] = fmaf(av[ii], bw[jj], acc[ii][jj]);
        }
        __syncthreads();
    }

    float4 b4 = *(const float4*)&bias[cw0 + tx * 4];
    float bc4[4] = {b4.x, b4.y, b4.z, b4.w};

    if (yb < 2) {
        _Float16* outp = (yb == 0) ? q16 : k16;
        #pragma unroll
        for (int ii = 0; ii < 4; ++ii) {
            f16x4 hv;
            #pragma unroll
            for (int jj = 0; jj < 4; ++jj) hv[jj] = (_Float16)(acc[ii][jj] + bc4[jj]);
            *(f16x4*)&outp[(size_t)(m0 + ty * 4 + ii) * 64 + tx * 4] = hv;
        }
    } else {
        #pragma unroll
        for (int jj = 0; jj < 4; ++jj) {
            f16x4 hv;
            #pragma unroll
            for (int ii = 0; ii < 4; ++ii) hv[ii] = (_Float16)(acc[ii][jj] + bc4[jj]);
            *(f16x4*)&Ts[(tx * 4 + jj) * 72 + ty * 4] = hv;
        }
        __syncthreads();
        {
            const int c = t >> 2, seg = t & 3;
            f16x8 r0 = *(const f16x8*)&Ts[c * 72 + seg * 16];
            f16x8 r1 = *(const f16x8*)&Ts[c * 72 + seg * 16 + 8];
            *(f16x8*)&vT[(size_t)(cw0 + c) * NN + m0 + seg * 16]     = r0;
            *(f16x8*)&vT[(size_t)(cw0 + c) * NN + m0 + seg * 16 + 8] = r1;
        }
    }
}

// ---------------------------------------------------------------------------
// K2: scores = k16 @ q16^T via f16 MFMA, no LDS. 128x128 per block, 4 waves.
// Stores packed (hi, lo) f16x2 per score — single b32 store.
// ---------------------------------------------------------------------------
__global__ __launch_bounds__(256) void k_scores(
    const _Float16* __restrict__ q16, const _Float16* __restrict__ k16,
    f16x2* __restrict__ schl)
{
    const int t    = threadIdx.x;
    const int lane = t & 63;
    const int w    = t >> 6;
    const int col  = lane & 15;
    const int q    = lane >> 4;

    const int i0 = blockIdx.y * 128 + (w >> 1) * 64;
    const int j0 = blockIdx.x * 128 + (w & 1) * 64;

    f32x4 acc[4][4] = {};

    #pragma unroll
    for (int ks = 0; ks < 2; ++ks) {
        f16x8 a[4], b[4];
        #pragma unroll
        for (int f = 0; f < 4; ++f) {
            a[f] = *(const f16x8*)&k16[(size_t)(i0 + f * 16 + col) * 64 + ks * 32 + q * 8];
            b[f] = *(const f16x8*)&q16[(size_t)(j0 + f * 16 + col) * 64 + ks * 32 + q * 8];
        }
        #pragma unroll
        for (int fm = 0; fm < 4; ++fm)
            #pragma unroll
            for (int fn = 0; fn < 4; ++fn)
                acc[fm][fn] = __builtin_amdgcn_mfma_f32_16x16x32_f16(a[fm], b[fn], acc[fm][fn], 0, 0, 0);
    }

    #pragma unroll
    for (int fm = 0; fm < 4; ++fm)
        #pragma unroll
        for (int fn = 0; fn < 4; ++fn)
            #pragma unroll
            for (int r = 0; r < 4; ++r) {
                const size_t idx = (size_t)(i0 + fm * 16 + q * 4 + r) * NN + j0 + fn * 16 + col;
                const float val = acc[fm][fn][r];
                const _Float16 h = (_Float16)val;
                f16x2 pk; pk[0] = h; pk[1] = (_Float16)(val - (float)h);
                schl[idx] = pk;
            }
}

// ---------------------------------------------------------------------------
// K3: per-edge MLP + row softmax. One block per row, 4 independent waves.
// Zero LDS memory in the main loop; all permutations via shfl.
// FIX vs R7: the C1->B2 register transpose now shuffles ALL FOUR packs over
// both source lanes (8 shfls) and selects pA/pB POST-shfl by the DEST quad.
// (R7 selected pre-shfl by the source quad -> dest q=1/q=2 got swapped
// feature halves.)
// ---------------------------------------------------------------------------
__global__ __launch_bounds__(256) void k_mlp(
    const f16x2* __restrict__ schl,
    const float* __restrict__ adj, const float* __restrict__ dense,
    const float* __restrict__ W1, const float* __restrict__ b1,
    const float* __restrict__ W2, const float* __restrict__ b2,
    const float* __restrict__ W3,
    _Float16* __restrict__ focus)   // row stride 2*NN halves (overlays schl)
{
    __shared__ float red[8];

    const int t    = threadIdx.x;
    const int lane = t & 63;
    const int w    = t >> 6;
    const int col  = lane & 15;
    const int q    = lane >> 4;
    const int i    = blockIdx.x;

    // ---- layer-1 A fragments (nonzero only on quad 0: k slots 0..4) ----
    f16x8 w1a0 = {}, w1a1 = {};
    if (q == 0) {
        const float w0a = W1[col],      w0b = W1[col + 16];
        const _Float16 h0a = (_Float16)w0a, h0b = (_Float16)w0b;
        w1a0[0] = h0a; w1a0[1] = h0a;
        w1a0[2] = (_Float16)W1[32 + col];
        w1a0[3] = (_Float16)W1[64 + col];
        w1a0[4] = (_Float16)(w0a - (float)h0a);
        w1a1[0] = h0b; w1a1[1] = h0b;
        w1a1[2] = (_Float16)W1[32 + col + 16];
        w1a1[3] = (_Float16)W1[64 + col + 16];
        w1a1[4] = (_Float16)(w0b - (float)h0b);
    }
    // ---- layer-2 A fragments ----
    f16x8 w2f0, w2f1;
    #pragma unroll
    for (int j = 0; j < 8; ++j) {
        w2f0[j] = (_Float16)W2[(q * 8 + j) * 32 + col];
        w2f1[j] = (_Float16)W2[(q * 8 + j) * 32 + col + 16];
    }
    // ---- biases / W3 (indexed by feat = q*4+r) ----
    f32x4 c1a, c1b, c2a, c2b, w3v, w3v2;
    #pragma unroll
    for (int r = 0; r < 4; ++r) {
        c1a[r]  = b1[q * 4 + r];
        c1b[r]  = b1[16 + q * 4 + r];
        c2a[r]  = b2[q * 4 + r];
        c2b[r]  = b2[16 + q * 4 + r];
        w3v[r]  = W3[q * 4 + r];
        w3v2[r] = W3[16 + q * 4 + r];
    }
    // shfl source lanes for the C1 -> B2 register transpose
    const int idxA = ((2 * q) & 3) * 16 + col;       // src quads 0/2
    const int idxB = ((2 * q + 1) & 3) * 16 + col;   // src quads 1/3
    const bool qlo = (q < 2);                        // dest-side pA/pB select

    const f16x2* srow = schl  + (size_t)i * NN;
    const float* arow = adj   + (size_t)i * NN;
    const float* drow = dense + (size_t)i * NN;

    float lg[8];

    for (int c = 0; c < 8; ++c) {
        const int jj = w * 512 + c * 64 + lane;

        // per-lane edge feats packed into 3 b32 regs
        const int u_sa = __builtin_bit_cast(int, srow[jj]);              // (s_hi, s_lo)
        const int u_ad = __builtin_bit_cast(int,
            __builtin_amdgcn_cvt_pkrtz(arow[jj], drow[jj]));             // (a, d)
        const int u_s0 = u_sa & 0xFFFF;                                  // (s_hi, 0)

        float lgc = 0.f;
        #pragma unroll
        for (int st = 0; st < 4; ++st) {
            const int src = st * 16 + col;
            // gather 16 edges' feats into quad-0 lanes (B-operand of layer 1)
            int e0 = __shfl(u_sa, src, 64);
            int e1 = __shfl(u_ad, src, 64);
            int e2 = __shfl(u_s0, src, 64);
            if (q != 0) { e0 = 0; e1 = 0; e2 = 0; }
            i32x4 bv = {e0, e1, e2, 0};
            f16x8 B1 = __builtin_bit_cast(f16x8, bv);

            f32x4 hpA = __builtin_amdgcn_mfma_f32_16x16x32_f16(w1a0, B1, c1a, 0, 0, 0);
            f32x4 hpB = __builtin_amdgcn_mfma_f32_16x16x32_f16(w1a1, B1, c1b, 0, 0, 0);

            // relu + pack adjacent feat pairs (per edge = col of C1)
            const int pA0 = __builtin_bit_cast(int, __builtin_amdgcn_cvt_pkrtz(fmaxf(hpA[0], 0.f), fmaxf(hpA[1], 0.f)));
            const int pA1 = __builtin_bit_cast(int, __builtin_amdgcn_cvt_pkrtz(fmaxf(hpA[2], 0.f), fmaxf(hpA[3], 0.f)));
            const int pB0 = __builtin_bit_cast(int, __builtin_amdgcn_cvt_pkrtz(fmaxf(hpB[0], 0.f), fmaxf(hpB[1], 0.f)));
            const int pB1 = __builtin_bit_cast(int, __builtin_amdgcn_cvt_pkrtz(fmaxf(hpB[2], 0.f), fmaxf(hpB[3], 0.f)));

            // register transpose: C1[feat][edge] -> B2[k=feat][n=edge].
            // 8 shfls (all packs, both src quads), select post-shfl by dest q.
            const int aA0 = __shfl(pA0, idxA, 64);
            const int aA1 = __shfl(pA1, idxA, 64);
            const int aB0 = __shfl(pB0, idxA, 64);
            const int aB1 = __shfl(pB1, idxA, 64);
            const int bA0 = __shfl(pA0, idxB, 64);
            const int bA1 = __shfl(pA1, idxB, 64);
            const int bB0 = __shfl(pB0, idxB, 64);
            const int bB1 = __shfl(pB1, idxB, 64);
            i32x4 b2v = { qlo ? aA0 : aB0, qlo ? aA1 : aB1,
                          qlo ? bA0 : bB0, qlo ? bA1 : bB1 };
            f16x8 B2 = __builtin_bit_cast(f16x8, b2v);

            f32x4 acc0 = __builtin_amdgcn_mfma_f32_16x16x32_f16(w2f0, B2, c2a, 0, 0, 0);
            f32x4 acc1 = __builtin_amdgcn_mfma_f32_16x16x32_f16(w2f1, B2, c2b, 0, 0, 0);

            float p = 0.f;
            #pragma unroll
            for (int r = 0; r < 4; ++r) {
                p = fmaf(fmaxf(acc0[r], 0.f), w3v[r],  p);
                p = fmaf(fmaxf(acc1[r], 0.f), w3v2[r], p);
            }
            p += __shfl_xor(p, 16, 64);
            p += __shfl_xor(p, 32, 64);
            lgc = (q == st) ? p : lgc;     // lane (q,col) keeps edge q*16+col
        }
        lg[c] = lgc;
    }

    // ---- row softmax (logits in registers; edge = w*512+c*64+q*16+col) ----
    float lmax = -1e30f;
    #pragma unroll
    for (int u = 0; u < 8; ++u) lmax = fmaxf(lmax, lg[u]);
    #pragma unroll
    for (int off = 32; off > 0; off >>= 1)
        lmax = fmaxf(lmax, __shfl_xor(lmax, off, 64));
    if (lane == 0) red[w] = lmax;
    __syncthreads();
    const float rmax = fmaxf(fmaxf(red[0], red[1]), fmaxf(red[2], red[3]));

    float lsum = 0.f;
    #pragma unroll
    for (int u = 0; u < 8; ++u) { lg[u] = __expf(lg[u] - rmax); lsum += lg[u]; }
    #pragma unroll
    for (int off = 32; off > 0; off >>= 1)
        lsum += __shfl_xor(lsum, off, 64);
    if (lane == 0) red[4 + w] = lsum;
    __syncthreads();
    const float inv = 1.f / (red[4] + red[5] + red[6] + red[7]);

    _Float16* hrow = focus + (size_t)i * 2 * NN;
    const int eb = w * 512 + q * 16 + col;
    #pragma unroll
    for (int u = 0; u < 8; ++u)
        hrow[eb + u * 64] = (_Float16)(lg[u] * inv);
}

// ---------------------------------------------------------------------------
// K4: feature = focus @ v via f16 MFMA, K split 4-way across waves + LDS
// reduce. grid (8,128). focus row stride = 2*NN halves (overlaid on schl).
// ---------------------------------------------------------------------------
__global__ __launch_bounds__(256) void k_feat(
    const _Float16* __restrict__ focus, const _Float16* __restrict__ vT,
    float* __restrict__ out)
{
    __shared__ float rbuf[3][64][8];

    const int t    = threadIdx.x;
    const int lane = t & 63;
    const int w    = t >> 6;
    const int col  = lane & 15;
    const int q    = lane >> 4;

    const int m0 = blockIdx.y * 16;
    const int n0 = blockIdx.x * 32;

    f32x4 acc0 = {}, acc1 = {};

    const size_t arow  = (size_t)(m0 + col) * (2 * NN);
    const size_t brow0 = (size_t)(n0 + col) * NN;
    const size_t brow1 = (size_t)(n0 + 16 + col) * NN;
    const int kb = w * 512 + q * 8;

    #pragma unroll 4
    for (int k0 = 0; k0 < 512; k0 += 32) {
        const int ko = kb + k0;
        f16x8 a  = *(const f16x8*)&focus[arow + ko];
        f16x8 b0 = *(const f16x8*)&vT[brow0 + ko];
        f16x8 b1 = *(const f16x8*)&vT[brow1 + ko];
        acc0 = __builtin_amdgcn_mfma_f32_16x16x32_f16(a, b0, acc0, 0, 0, 0);
        acc1 = __builtin_amdgcn_mfma_f32_16x16x32_f16(a, b1, acc1, 0, 0, 0);
    }

    if (w != 0) {
        *(float4*)&rbuf[w - 1][lane][0] = *(float4*)&acc0;
        *(float4*)&rbuf[w - 1][lane][4] = *(float4*)&acc1;
    }
    __syncthreads();

    if (w == 0) {
        #pragma unroll
        for (int j = 0; j < 3; ++j) {
            float4 p0 = *(const float4*)&rbuf[j][lane][0];
            float4 p1 = *(const float4*)&rbuf[j][lane][4];
            acc0[0] += p0.x; acc0[1] += p0.y; acc0[2] += p0.z; acc0[3] += p0.w;
            acc1[0] += p1.x; acc1[1] += p1.y; acc1[2] += p1.z; acc1[3] += p1.w;
        }
        #pragma unroll
        for (int r = 0; r < 4; ++r) {
            out[(size_t)(m0 + q * 4 + r) * DHH + n0 + col]      = acc0[r];
            out[(size_t)(m0 + q * 4 + r) * DHH + n0 + 16 + col] = acc1[r];
        }
    }
}

// ---------------------------------------------------------------------------
extern "C" void kernel_launch(void* const* d_in, const int* in_sizes, int n_in,
                              void* d_out, int out_size, void* d_ws, size_t ws_size,
                              hipStream_t stream) {
    const float* x     = (const float*)d_in[0];
    const float* adj   = (const float*)d_in[1];
    const float* dense = (const float*)d_in[2];
    const float* Wq    = (const float*)d_in[3];
    const float* bq    = (const float*)d_in[4];
    const float* Wk    = (const float*)d_in[5];
    const float* bk    = (const float*)d_in[6];
    const float* Wv    = (const float*)d_in[7];
    const float* bv    = (const float*)d_in[8];
    const float* W1    = (const float*)d_in[9];
    const float* b1    = (const float*)d_in[10];
    const float* W2    = (const float*)d_in[11];
    const float* b2    = (const float*)d_in[12];
    const float* W3    = (const float*)d_in[13];
    float* out = (float*)d_out;

    char* wsb = (char*)d_ws;
    _Float16* q16  = (_Float16*)(wsb);
    _Float16* k16  = (_Float16*)(wsb + 262144);
    _Float16* vT   = (_Float16*)(wsb + 524288);
    f16x2*    schl = (f16x2*)   (wsb + 1572864);
    _Float16* focus= (_Float16*)(wsb + 1572864);   // row stride 2*NN, in-place

    hipLaunchKernelGGL(k_qkv,    dim3(32, 6),  dim3(256), 0, stream,
                       x, Wq, bq, Wk, bk, Wv, bv, q16, k16, vT);
    hipLaunchKernelGGL(k_scores, dim3(16, 16), dim3(256), 0, stream, q16, k16, schl);
    hipLaunchKernelGGL(k_mlp,    dim3(2048),   dim3(256), 0, stream,
                       schl, adj, dense, W1, b1, W2, b2, W3, focus);
    hipLaunchKernelGGL(k_feat,   dim3(8, 128), dim3(256), 0, stream,
                       focus, vT, out);
}